// Round 14
// baseline (542.414 us; speedup 1.0000x reference)
//
#include <hip/hip_runtime.h>
#include <cstdio>

#define NRAYS 16384
#define SSTEPS 1024
#define GRES 128
#define NSAMP ((size_t)NRAYS * (size_t)SSTEPS)   // 16777216

// One thread per ray; serial 1024-sample loop; numpy-exact f32 rounding.
// OUTPUT IS FLOAT32 (d_out allocation = out_size*4 bytes, R13 evidence).
extern "C" __global__ void NeRFAccSampler_55791625175295_kernel(
    const float* rays_o,
    const float* rays_d,
    const float* jitter,
    const float* Wd,
    const float* bd,
    const unsigned char* binaries,
    float* out)
{
#pragma clang fp contract(off)
    const int ray = blockIdx.x * blockDim.x + threadIdx.x;
    if (ray >= NRAYS) return;

    const float STEP = (float)(2.0 * 1.7320508075688772 / 1024.0);

    const float ox = rays_o[3 * ray + 0], oy = rays_o[3 * ray + 1], oz = rays_o[3 * ray + 2];
    const float dx = rays_d[3 * ray + 0], dy = rays_d[3 * ray + 1], dz = rays_d[3 * ray + 2];
    const float jit = jitter[ray];
    const float w0 = Wd[0], w1 = Wd[1], w2 = Wd[2], bb = bd[0];

    const float ivx = 1.0f / dx, ivy = 1.0f / dy, ivz = 1.0f / dz;
    const float t0x = (-1.0f - ox) * ivx;
    const float t1x = ( 1.0f - ox) * ivx;
    const float t0y = (-1.0f - oy) * ivy;
    const float t1y = ( 1.0f - oy) * ivy;
    const float t0z = (-1.0f - oz) * ivz;
    const float t1z = ( 1.0f - oz) * ivz;
    const float tnx = t0x < t1x ? t0x : t1x, tXx = t0x > t1x ? t0x : t1x;
    const float tny = t0y < t1y ? t0y : t1y, tXy = t0y > t1y ? t0y : t1y;
    const float tnz = t0z < t1z ? t0z : t1z, tXz = t0z > t1z ? t0z : t1z;
    float t_near = tnx;
    if (tny > t_near) t_near = tny;
    if (tnz > t_near) t_near = tnz;
    if (t_near < 0.0f) t_near = 0.0f;
    float t_far = tXx;
    if (tXy < t_far) t_far = tXy;
    if (tXz < t_far) t_far = tXz;
    const bool hit = t_near < t_far;

    const size_t base = (size_t)ray * (size_t)SSTEPS;
    const float ray_f = (float)ray;

    float tau = 0.0f;   // inclusive running cumsum of sigma*STEP, exact np order

    for (int i = 0; i < SSTEPS; ++i) {
        const float fi = (float)i;
        const float t_start = t_near + (fi + jit) * STEP;
        const float t_end   = t_start + STEP;
        const float mid     = (t_start + t_end) * 0.5f;
        const float px = ox + dx * mid;
        const float py = oy + dy * mid;
        const float pz = oz + dz * mid;

        // idx = clip(floor((p+1)/2*128), 0, 127); (p+1)*64 pow2-exact.
        // clamp-then-truncate == floor-then-clip on [0,127]; also scrubs NaN.
        float vx = (px + 1.0f) * 64.0f;
        float vy = (py + 1.0f) * 64.0f;
        float vz = (pz + 1.0f) * 64.0f;
        if (!(vx > 0.0f)) vx = 0.0f;
        if (vx > 127.0f)  vx = 127.0f;
        if (!(vy > 0.0f)) vy = 0.0f;
        if (vy > 127.0f)  vy = 127.0f;
        if (!(vz > 0.0f)) vz = 0.0f;
        if (vz > 127.0f)  vz = 127.0f;
        const int flat = (((int)vx * GRES) + (int)vy) * GRES + (int)vz;
        const bool occ = binaries[flat] != 0;

        const bool valid = occ && (t_end < t_far) && hit;

        // sigma = relu(((px*w0 + py*w1) + pz*w2) + bb) -- np matmul sum order
        float sig = ((px * w0 + py * w1) + pz * w2) + bb;
        if (sig < 0.0f) sig = 0.0f;
        const float sstep = (valid ? sig : 0.0f) * STEP;

        const float incl = tau + sstep;     // np cumsum rounding
        const float excl = incl - sstep;    // np (tau - sigma*STEP) rounding
        tau = incl;

        const bool keep = valid && (__builtin_expf(-excl) > 1e-4f);

        const size_t o0 = base + (size_t)i;
        out[o0]             = ray_f;
        out[NSAMP + o0]     = keep ? t_start : 0.0f;
        out[2 * NSAMP + o0] = keep ? t_end   : 0.0f;
        out[3 * NSAMP + o0] = keep ? 1.0f    : 0.0f;
    }
}

extern "C" void kernel_launch(void* const* d_in, const int* in_sizes, int n_in,
                              void* d_out, int out_size, void* d_ws, size_t ws_size,
                              hipStream_t stream) {
    const float* rays_o           = (const float*)d_in[0];
    const float* rays_d           = (const float*)d_in[1];
    const float* jitter           = (const float*)d_in[2];
    const float* Wd               = (const float*)d_in[3];
    const float* bd               = (const float*)d_in[4];
    const unsigned char* binaries = (const unsigned char*)d_in[5];
    float* out                    = (float*)d_out;

    NeRFAccSampler_55791625175295_kernel<<<NRAYS / 64, 64, 0, stream>>>(
        rays_o, rays_d, jitter, Wd, bd, binaries, out);

    // Lightweight diagnostics, non-capture (correctness) pass only.
    hipStreamCaptureStatus st = hipStreamCaptureStatusNone;
    hipError_t eq = hipStreamIsCapturing(stream, &st);
    if (eq == hipSuccess && st == hipStreamCaptureStatusNone) {
        hipError_t es = hipDeviceSynchronize();
        float tail = -1.0f, mid = -1.0f;
        (void)hipMemcpy(&tail, (const char*)d_out + (NSAMP - 1) * 4, 4, hipMemcpyDeviceToHost);
        (void)hipMemcpy(&mid,  (const char*)d_out + (NSAMP / 2) * 4, 4, hipMemcpyDeviceToHost);
        fprintf(stderr, "KLDBG f32 sync=%s out0_tail=%.1f (exp 16383) out0_mid=%.1f (exp 8192)\n",
                hipGetErrorString(es), tail, mid);
        fflush(stderr);
    }
}

// Round 15
// 49.773 us; speedup vs baseline: 10.8977x; 10.8977x over previous
//
#include <hip/hip_runtime.h>

#define NRAYS 16384
#define SSTEPS 1024
#define GRES 128
#define NSAMP ((size_t)NRAYS * (size_t)SSTEPS)   // 16777216

// One 64-lane wave per ray; lane owns 4 consecutive samples per chunk,
// 4 chunks of 256 samples. Coalesced float4 stores (1 KB/wave/output).
// f32 math with contraction off == numpy rounding; keep-test via direct
// threshold compare (monotone-equivalent to exp(-x) > 1e-4).
extern "C" __global__ __launch_bounds__(256) void NeRFAccSampler_55791625175295_kernel(
    const float* __restrict__ rays_o,
    const float* __restrict__ rays_d,
    const float* __restrict__ jitter,
    const float* __restrict__ Wd,
    const float* __restrict__ bd,
    const unsigned char* __restrict__ binaries,
    float* __restrict__ out)
{
#pragma clang fp contract(off)
    const int tid  = blockIdx.x * 256 + (int)threadIdx.x;
    const int ray  = tid >> 6;
    const int lane = (int)threadIdx.x & 63;
    if (ray >= NRAYS) return;

    const float STEP = (float)(2.0 * 1.7320508075688772 / 1024.0);
    const float KEEP_THR = 9.2103405f;   // fl32(-ln(1e-4)); excl < THR <=> T > 1e-4

    const float ox = rays_o[3 * ray + 0], oy = rays_o[3 * ray + 1], oz = rays_o[3 * ray + 2];
    const float dx = rays_d[3 * ray + 0], dy = rays_d[3 * ray + 1], dz = rays_d[3 * ray + 2];
    const float jit = jitter[ray];
    const float w0 = Wd[0], w1 = Wd[1], w2 = Wd[2], bb = bd[0];

    // slab test vs [-1,1]^3 (numpy-identical f32 rounding; inputs finite)
    const float ivx = 1.0f / dx, ivy = 1.0f / dy, ivz = 1.0f / dz;
    const float t0x = (-1.0f - ox) * ivx;
    const float t1x = ( 1.0f - ox) * ivx;
    const float t0y = (-1.0f - oy) * ivy;
    const float t1y = ( 1.0f - oy) * ivy;
    const float t0z = (-1.0f - oz) * ivz;
    const float t1z = ( 1.0f - oz) * ivz;
    const float tnx = t0x < t1x ? t0x : t1x, tXx = t0x > t1x ? t0x : t1x;
    const float tny = t0y < t1y ? t0y : t1y, tXy = t0y > t1y ? t0y : t1y;
    const float tnz = t0z < t1z ? t0z : t1z, tXz = t0z > t1z ? t0z : t1z;
    float t_near = tnx;
    if (tny > t_near) t_near = tny;
    if (tnz > t_near) t_near = tnz;
    if (t_near < 0.0f) t_near = 0.0f;
    float t_far = tXx;
    if (tXy < t_far) t_far = tXy;
    if (tXz < t_far) t_far = tXz;
    const bool hit = t_near < t_far;

    const size_t base  = (size_t)ray * (size_t)SSTEPS;
    const float  ray_f = (float)ray;
    const float4 o0v   = make_float4(ray_f, ray_f, ray_f, ray_f);

    float tau = 0.0f;   // carried transmittance integral (sum of sigma*STEP)

    for (int it = 0; it < 4; ++it) {
        const int s0 = (it << 8) + (lane << 2);   // first of this lane's 4 samples

        float ts[4], te[4], loc[4];
        bool  vld[4];
        float sum = 0.0f;

        #pragma unroll
        for (int k = 0; k < 4; ++k) {
            const float fi = (float)(s0 + k);
            const float t_start = t_near + (fi + jit) * STEP;
            const float t_end   = t_start + STEP;
            const float mid     = (t_start + t_end) * 0.5f;
            const float px = ox + dx * mid;
            const float py = oy + dy * mid;
            const float pz = oz + dz * mid;

            // cell = clip(floor((p+1)*64), 0, 127); clamp-then-trunc, NaN-safe
            float vx = (px + 1.0f) * 64.0f;
            float vy = (py + 1.0f) * 64.0f;
            float vz = (pz + 1.0f) * 64.0f;
            if (!(vx > 0.0f)) vx = 0.0f;
            if (vx > 127.0f)  vx = 127.0f;
            if (!(vy > 0.0f)) vy = 0.0f;
            if (vy > 127.0f)  vy = 127.0f;
            if (!(vz > 0.0f)) vz = 0.0f;
            if (vz > 127.0f)  vz = 127.0f;
            const int flat = (((int)vx * GRES) + (int)vy) * GRES + (int)vz;
            const bool occ = binaries[flat] != 0;

            const bool valid = occ && (t_end < t_far) && hit;

            float sig = ((px * w0 + py * w1) + pz * w2) + bb;
            if (sig < 0.0f) sig = 0.0f;
            const float sstep = (valid ? sig : 0.0f) * STEP;

            ts[k]  = t_start;
            te[k]  = t_end;
            vld[k] = valid;
            loc[k] = sum;          // lane-local exclusive prefix
            sum    = sum + sstep;
        }

        // wave-level inclusive scan of lane sums (6 shuffle steps)
        float run = sum;
        #pragma unroll
        for (int d = 1; d < 64; d <<= 1) {
            const float y = __shfl_up(run, d, 64);
            if (lane >= d) run += y;
        }
        const float exbase = tau + (run - sum);   // exclusive prefix entering this lane
        tau += __shfl(run, 63, 64);               // wave total -> carried tau

        float o1[4], o2[4], o3[4];
        #pragma unroll
        for (int k = 0; k < 4; ++k) {
            const float excl = exbase + loc[k];
            const bool keep  = vld[k] && (excl < KEEP_THR);
            o1[k] = keep ? ts[k] : 0.0f;
            o2[k] = keep ? te[k] : 0.0f;
            o3[k] = keep ? 1.0f  : 0.0f;
        }

        const size_t o = base + (size_t)s0;
        *reinterpret_cast<float4*>(&out[o])             = o0v;
        *reinterpret_cast<float4*>(&out[NSAMP + o])     = make_float4(o1[0], o1[1], o1[2], o1[3]);
        *reinterpret_cast<float4*>(&out[2 * NSAMP + o]) = make_float4(o2[0], o2[1], o2[2], o2[3]);
        *reinterpret_cast<float4*>(&out[3 * NSAMP + o]) = make_float4(o3[0], o3[1], o3[2], o3[3]);
    }
}

extern "C" void kernel_launch(void* const* d_in, const int* in_sizes, int n_in,
                              void* d_out, int out_size, void* d_ws, size_t ws_size,
                              hipStream_t stream) {
    const float* rays_o           = (const float*)d_in[0];
    const float* rays_d           = (const float*)d_in[1];
    const float* jitter           = (const float*)d_in[2];
    const float* Wd               = (const float*)d_in[3];
    const float* bd               = (const float*)d_in[4];
    const unsigned char* binaries = (const unsigned char*)d_in[5];
    float* out                    = (float*)d_out;

    // 4 waves (4 rays) per 256-thread block; 4096 blocks = 16384 waves.
    NeRFAccSampler_55791625175295_kernel<<<NRAYS / 4, 256, 0, stream>>>(
        rays_o, rays_d, jitter, Wd, bd, binaries, out);
}